// Round 1
// baseline (153.682 us; speedup 1.0000x reference)
//
#include <hip/hip_runtime.h>
#include <math.h>

#define N_V 100000
#define N_J 24
#define N_BETAS 300
#define N_POSE 207
#define JSPLIT 8

__constant__ int c_parents[N_J] = {0,0,0,0,1,2,3,4,5,6,7,8,9,9,9,12,13,14,16,17,18,19,20,21};

// ---------------- K1: rodrigues + lrotmin ----------------
__global__ void k_rodrigues(const float* __restrict__ pose,
                            float* __restrict__ ws_R,
                            float* __restrict__ ws_lrot) {
    __shared__ float Rsh[N_J][9];
    int t = threadIdx.x;
    if (t < N_J) {
        float x = pose[t*3+0], y = pose[t*3+1], z = pose[t*3+2];
        float th = sqrtf(x*x + y*y + z*z + 1e-16f);
        float inv = 1.0f / th;
        float rx = x*inv, ry = y*inv, rz = z*inv;
        float c = cosf(th), s = sinf(th), o = 1.0f - c;
        float R[9];
        R[0] = c + o*rx*rx;      R[1] = o*rx*ry - s*rz;  R[2] = o*rx*rz + s*ry;
        R[3] = o*ry*rx + s*rz;   R[4] = c + o*ry*ry;     R[5] = o*ry*rz - s*rx;
        R[6] = o*rz*rx - s*ry;   R[7] = o*rz*ry + s*rx;  R[8] = c + o*rz*rz;
        #pragma unroll
        for (int i = 0; i < 9; ++i) { Rsh[t][i] = R[i]; ws_R[t*9+i] = R[i]; }
    }
    __syncthreads();
    for (int i = t; i < N_POSE; i += blockDim.x) {
        int j = i / 9 + 1, e = i % 9;
        float v = Rsh[j][e];
        if (e == 0 || e == 4 || e == 8) v -= 1.0f;
        ws_lrot[i] = v;
    }
}

// ---------------- K2: per-vertex v_shaped + v_posed (wave per vertex) -------
__global__ __launch_bounds__(256) void k_vertex(
        const float* __restrict__ shapedirs, const float* __restrict__ posedirs,
        const float* __restrict__ v_template, const float* __restrict__ beta,
        const float* __restrict__ ws_lrot,
        float* __restrict__ ws_vs, float* __restrict__ ws_vp) {
    __shared__ __align__(16) float beta_s[N_BETAS];
    __shared__ float lrot_s[N_POSE];
    int t = threadIdx.x;
    for (int i = t; i < N_BETAS; i += 256) beta_s[i] = beta[i];
    for (int i = t; i < N_POSE;  i += 256) lrot_s[i] = ws_lrot[i];
    __syncthreads();

    int wave = t >> 6, lane = t & 63;
    int v = blockIdx.x * 4 + wave;
    if (v >= N_V) return;

    // ---- shapedirs · beta : 900 floats = 225 float4 (16B aligned: 3600B/vertex)
    const float4* sbase = (const float4*)(shapedirs + (size_t)v * 900);
    float a0 = 0.f, a1 = 0.f, a2 = 0.f;
    #pragma unroll
    for (int it = 0; it < 4; ++it) {
        int i = lane + it * 64;
        if (it < 3 || i < 225) {
            float4 sv = sbase[i];
            int d  = (i >= 150) ? 2 : ((i >= 75) ? 1 : 0);
            int k4 = i - d * 75;
            float4 bv = *(const float4*)(beta_s + k4 * 4);
            float c = sv.x*bv.x + sv.y*bv.y + sv.z*bv.z + sv.w*bv.w;
            if (d == 0) a0 += c; else if (d == 1) a1 += c; else a2 += c;
        }
    }
    #pragma unroll
    for (int off = 32; off; off >>= 1) {
        a0 += __shfl_xor(a0, off); a1 += __shfl_xor(a1, off); a2 += __shfl_xor(a2, off);
    }
    float vsd = 0.f;
    if (lane < 3) {
        vsd = (lane == 0 ? a0 : (lane == 1 ? a1 : a2)) + v_template[v*3 + lane];
        ws_vs[v*3 + lane] = vsd;
    }

    // ---- posedirs · lrotmin : 621 floats (only 4B-aligned -> scalar loads)
    const float* pbase = posedirs + (size_t)v * 621;
    float p0 = 0.f, p1 = 0.f, p2 = 0.f;
    #pragma unroll
    for (int it = 0; it < 10; ++it) {
        int i = lane + it * 64;
        if (it < 9 || i < 621) {
            float val = pbase[i];
            int d = (i >= 414) ? 2 : ((i >= 207) ? 1 : 0);
            int p = i - d * 207;
            float c = val * lrot_s[p];
            if (d == 0) p0 += c; else if (d == 1) p1 += c; else p2 += c;
        }
    }
    #pragma unroll
    for (int off = 32; off; off >>= 1) {
        p0 += __shfl_xor(p0, off); p1 += __shfl_xor(p1, off); p2 += __shfl_xor(p2, off);
    }
    if (lane < 3) {
        float pd = (lane == 0 ? p0 : (lane == 1 ? p1 : p2));
        ws_vp[v*3 + lane] = vsd + pd;
    }
}

// ---------------- K3: J = J_regressor @ v_shaped (block partials) ----------
__global__ __launch_bounds__(256) void k_jreg(const float* __restrict__ Jr,
                                              const float* __restrict__ vs,
                                              float* __restrict__ jpart) {
    int j = blockIdx.x / JSPLIT;
    int s = blockIdx.x % JSPLIT;
    const int chunk = N_V / JSPLIT;   // 12500
    int v0 = s * chunk;
    int t = threadIdx.x;
    const float* row = Jr + (size_t)j * N_V;
    float a0 = 0.f, a1 = 0.f, a2 = 0.f;
    for (int v = v0 + t; v < v0 + chunk; v += 256) {
        float w = row[v];
        a0 += w * vs[v*3+0]; a1 += w * vs[v*3+1]; a2 += w * vs[v*3+2];
    }
    #pragma unroll
    for (int off = 32; off; off >>= 1) {
        a0 += __shfl_xor(a0, off); a1 += __shfl_xor(a1, off); a2 += __shfl_xor(a2, off);
    }
    __shared__ float red[4][3];
    int wave = t >> 6, lane = t & 63;
    if (lane == 0) { red[wave][0] = a0; red[wave][1] = a1; red[wave][2] = a2; }
    __syncthreads();
    if (t == 0) {
        float r0 = red[0][0]+red[1][0]+red[2][0]+red[3][0];
        float r1 = red[0][1]+red[1][1]+red[2][1]+red[3][1];
        float r2 = red[0][2]+red[1][2]+red[2][2]+red[3][2];
        jpart[(j*JSPLIT+s)*3+0] = r0;
        jpart[(j*JSPLIT+s)*3+1] = r1;
        jpart[(j*JSPLIT+s)*3+2] = r2;
    }
}

// ---------------- K4: reduce J + kinematic chain -> G' [24][12] ------------
__global__ void k_chain(const float* __restrict__ jpart,
                        const float* __restrict__ ws_R,
                        float* __restrict__ ws_G) {
    __shared__ float J[N_J][3];
    __shared__ float G[N_J][16];
    int t = threadIdx.x;
    if (t < N_J * 3) {
        int j = t / 3, d = t % 3;
        float s = 0.f;
        #pragma unroll
        for (int k = 0; k < JSPLIT; ++k) s += jpart[(j*JSPLIT+k)*3 + d];
        J[j][d] = s;
    }
    __syncthreads();
    if (t < 16) {
        int a = t / 4, b = t % 4;
        float g;
        if (a < 3) g = (b < 3) ? ws_R[a*3 + b] : J[0][a];
        else       g = (b == 3) ? 1.f : 0.f;
        G[0][t] = g;
    }
    __syncthreads();
    for (int i = 1; i < N_J; ++i) {
        int p = c_parents[i];
        if (t < 16) {
            int a = t / 4, b = t % 4;
            float acc = 0.f;
            #pragma unroll
            for (int k = 0; k < 4; ++k) {
                float Ak;
                if (k < 3) Ak = (b < 3) ? ws_R[i*9 + k*3 + b] : (J[i][k] - J[p][k]);
                else       Ak = (b == 3) ? 1.f : 0.f;
                acc += G[p][a*4 + k] * Ak;
            }
            G[i][t] = acc;
        }
        __syncthreads();
    }
    // G' rows 0..2 : [R | t - R*J]  (12 floats per joint)
    if (t < N_J * 12) {
        int j = t / 12, r = t % 12, a = r / 4, b = r % 4;
        float g = G[j][a*4 + b];
        if (b == 3)
            g -= G[j][a*4+0]*J[j][0] + G[j][a*4+1]*J[j][1] + G[j][a*4+2]*J[j][2];
        ws_G[t] = g;
    }
}

// ---------------- K5: skinning --------------------------------------------
__global__ __launch_bounds__(256) void k_skin(const float* __restrict__ w,
                                              const float* __restrict__ ws_G,
                                              const float* __restrict__ vp,
                                              float* __restrict__ out) {
    __shared__ float G[N_J * 12];
    int t = threadIdx.x;
    for (int i = t; i < N_J * 12; i += 256) G[i] = ws_G[i];
    __syncthreads();
    int v = blockIdx.x * 256 + t;
    if (v >= N_V) return;
    float T[12];
    #pragma unroll
    for (int r = 0; r < 12; ++r) T[r] = 0.f;
    const float4* wv = (const float4*)(w + (size_t)v * 24);
    #pragma unroll
    for (int q = 0; q < 6; ++q) {
        float4 ww = wv[q];
        float wj[4] = {ww.x, ww.y, ww.z, ww.w};
        #pragma unroll
        for (int jj = 0; jj < 4; ++jj) {
            const float* g = &G[(q*4 + jj) * 12];
            #pragma unroll
            for (int r = 0; r < 12; ++r) T[r] += wj[jj] * g[r];
        }
    }
    float p0 = vp[v*3+0], p1 = vp[v*3+1], p2 = vp[v*3+2];
    out[v*3+0] = T[0]*p0 + T[1]*p1 + T[2]*p2  + T[3];
    out[v*3+1] = T[4]*p0 + T[5]*p1 + T[6]*p2  + T[7];
    out[v*3+2] = T[8]*p0 + T[9]*p1 + T[10]*p2 + T[11];
}

// ---------------- launcher --------------------------------------------------
extern "C" void kernel_launch(void* const* d_in, const int* in_sizes, int n_in,
                              void* d_out, int out_size, void* d_ws, size_t ws_size,
                              hipStream_t stream) {
    const float* beta       = (const float*)d_in[0];
    const float* pose       = (const float*)d_in[1];
    const float* v_template = (const float*)d_in[2];
    const float* Jr         = (const float*)d_in[3];
    const float* skin_w     = (const float*)d_in[4];
    const float* shapedirs  = (const float*)d_in[5];
    const float* posedirs   = (const float*)d_in[6];
    float* out = (float*)d_out;

    float* ws      = (float*)d_ws;
    float* ws_R    = ws;            // 216
    float* ws_lrot = ws + 256;      // 207
    float* ws_vs   = ws + 512;      // 300000
    float* ws_vp   = ws + 300800;   // 300000
    float* ws_jp   = ws + 600832;   // 24*8*3 = 576
    float* ws_G    = ws + 601472;   // 288

    k_rodrigues<<<1, 256, 0, stream>>>(pose, ws_R, ws_lrot);
    k_vertex<<<N_V / 4, 256, 0, stream>>>(shapedirs, posedirs, v_template, beta,
                                          ws_lrot, ws_vs, ws_vp);
    k_jreg<<<N_J * JSPLIT, 256, 0, stream>>>(Jr, ws_vs, ws_jp);
    k_chain<<<1, 320, 0, stream>>>(ws_jp, ws_R, ws_G);
    k_skin<<<(N_V + 255) / 256, 256, 0, stream>>>(skin_w, ws_G, ws_vp, out);
}